// Round 1
// baseline (803.319 us; speedup 1.0000x reference)
//
#include <hip/hip_runtime.h>
#include <hip/hip_bf16.h>
#include <math.h>

#define NTOK 4096
#define HDIM 768
#define FDIM 3072
#define NEXP 4

typedef __attribute__((ext_vector_type(4))) float f32x4;
typedef __attribute__((ext_vector_type(8))) short s16x8;

__device__ __forceinline__ unsigned short f2bf(float f) {
    union { float f; unsigned int u; } v; v.f = f;
    unsigned int u = v.u;
    unsigned int r = (u + 0x7fffu + ((u >> 16) & 1u)) >> 16;
    return (unsigned short)r;
}

// ---------------- routing: logits, softmax-max, argmax for both routers ----------
__global__ void __launch_bounds__(256) route_kernel(
    const float* __restrict__ h, const float* __restrict__ Wsc, const float* __restrict__ bsc,
    const float* __restrict__ Wsu, const float* __restrict__ bsu,
    int* __restrict__ route_c, float* __restrict__ pmax_c,
    int* __restrict__ route_u, float* __restrict__ pmax_u,
    int* __restrict__ counts /* 8 ints, zeroed here by block 0 */)
{
    int i = blockIdx.x, t = threadIdx.x;
    if (i == 0 && t < 8) counts[t] = 0;
    const float* hr = h + (size_t)i * HDIM;
    float ac[4] = {0.f,0.f,0.f,0.f}, au[4] = {0.f,0.f,0.f,0.f};
    for (int k = t; k < HDIM; k += 256) {
        float x = hr[k];
        #pragma unroll
        for (int j = 0; j < 4; ++j) {
            ac[j] += x * Wsc[k*4 + j];
            au[j] += x * Wsu[k*4 + j];
        }
    }
    __shared__ float red[256][8];
    #pragma unroll
    for (int j = 0; j < 4; ++j) { red[t][j] = ac[j]; red[t][4+j] = au[j]; }
    __syncthreads();
    for (int s = 128; s > 0; s >>= 1) {
        if (t < s) {
            #pragma unroll
            for (int j = 0; j < 8; ++j) red[t][j] += red[t+s][j];
        }
        __syncthreads();
    }
    if (t == 0) {
        float lc[4], lu[4];
        #pragma unroll
        for (int j = 0; j < 4; ++j) { lc[j] = red[0][j] + bsc[j]; lu[j] = red[0][4+j] + bsu[j]; }
        int bc = 0; float mc = lc[0];
        #pragma unroll
        for (int j = 1; j < 4; ++j) if (lc[j] > mc) { mc = lc[j]; bc = j; }
        float dc = 0.f;
        #pragma unroll
        for (int j = 0; j < 4; ++j) dc += expf(lc[j] - mc);
        route_c[i] = bc; pmax_c[i] = 1.0f / dc;
        int bu = 0; float mu = lu[0];
        #pragma unroll
        for (int j = 1; j < 4; ++j) if (lu[j] > mu) { mu = lu[j]; bu = j; }
        float du = 0.f;
        #pragma unroll
        for (int j = 0; j < 4; ++j) du += expf(lu[j] - mu);
        route_u[i] = bu; pmax_u[i] = 1.0f / du;
    }
}

// ---------------- capacity-drop: rank within expert group by (-pmax, index) ------
__global__ void __launch_bounds__(256) rank_kernel(
    const int* __restrict__ rc, const float* __restrict__ pc,
    int* __restrict__ dropped, int capacity)
{
    int i = blockIdx.x, t = threadIdx.x;
    int e = rc[i]; float pi = pc[i];
    int cnt = 0;
    for (int j = t; j < NTOK; j += 256) {
        if (rc[j] == e) {
            float pj = pc[j];
            if (pj > pi || (pj == pi && j < i)) cnt++;
        }
    }
    __shared__ int red[256];
    red[t] = cnt; __syncthreads();
    for (int s = 128; s > 0; s >>= 1) {
        if (t < s) red[t] += red[t+s];
        __syncthreads();
    }
    if (t == 0) dropped[i] = (red[0] >= capacity) ? 1 : 0;
}

// ---------------- histogram ------------------------------------------------------
__global__ void __launch_bounds__(256) count_kernel(
    const int* __restrict__ rc, const int* __restrict__ ru,
    const int* __restrict__ dropped, int* __restrict__ counts)
{
    int i = blockIdx.x * 256 + threadIdx.x;
    if (i >= NTOK) return;
    atomicAdd(&counts[rc[i]], 1);
    if (dropped[i]) atomicAdd(&counts[4 + ru[i]], 1);
}

__global__ void offsets_kernel(const int* __restrict__ counts,
                               int* __restrict__ offc, int* __restrict__ offu,
                               int* __restrict__ cur)
{
    if (threadIdx.x == 0 && blockIdx.x == 0) {
        int oc = 0, ou = 0;
        for (int e = 0; e < 4; ++e) { offc[e] = oc; oc += counts[e]; }
        offc[4] = oc;
        for (int e = 0; e < 4; ++e) { offu[e] = ou; ou += counts[4+e]; }
        offu[4] = ou;
        for (int j = 0; j < 8; ++j) cur[j] = 0;
    }
}

__global__ void __launch_bounds__(256) scatter_kernel(
    const int* __restrict__ rc, const int* __restrict__ ru, const int* __restrict__ dropped,
    const int* __restrict__ offc, const int* __restrict__ offu,
    int* __restrict__ cur, int* __restrict__ permc, int* __restrict__ permu)
{
    int i = blockIdx.x * 256 + threadIdx.x;
    if (i >= NTOK) return;
    int e = rc[i];
    int p = offc[e] + atomicAdd(&cur[e], 1);
    permc[p] = i;
    if (dropped[i]) {
        int eu = ru[i];
        int q = offu[eu] + atomicAdd(&cur[4 + eu], 1);
        permu[q] = i;
    }
}

// ---------------- gather tokens (sorted order) into bf16 -------------------------
__global__ void __launch_bounds__(256) gather_kernel(
    const float* __restrict__ h, const int* __restrict__ perm,
    const int* __restrict__ nvalid, unsigned short* __restrict__ Xs)
{
    int pos = blockIdx.x;
    if (pos >= *nvalid) return;
    int t = threadIdx.x;
    if (t >= 192) return;
    int tok = perm[pos];
    const float4 v = *(const float4*)(h + (size_t)tok * HDIM + t * 4);
    ushort4 o;
    o.x = f2bf(v.x); o.y = f2bf(v.y); o.z = f2bf(v.z); o.w = f2bf(v.w);
    *(ushort4*)(Xs + (size_t)pos * HDIM + t * 4) = o;
}

// ---------------- grouped GEMM: 128x128 tile, MFMA 16x16x32 bf16 -----------------
// A: bf16 [rows][K] in sorted-position space. B: fp32 [NEXP][K][N] (converted in staging).
// doGelu: out = bf16 G[pos][N] with exact gelu. else: out = fp32 Yout[perm[pos]][N] (+= if doAdd)
__global__ void __launch_bounds__(256) ffn_gemm(
    const unsigned short* __restrict__ A, const float* __restrict__ B,
    const float* __restrict__ bias, const int* __restrict__ offs,
    unsigned short* __restrict__ Gout, float* __restrict__ Yout,
    const int* __restrict__ perm, int K, int N, int doGelu, int doAdd)
{
    int e = blockIdx.z, mt = blockIdx.y, nt = blockIdx.x;
    int off = offs[e];
    int cnt = offs[e+1] - off;
    if (mt * 128 >= cnt) return;

    __shared__ unsigned short As[128][40];
    __shared__ unsigned short Bs[128][40];

    int tid = threadIdx.x;
    int lane = tid & 63, wave = tid >> 6;
    int wm = wave >> 1, wn = wave & 1;
    int quad = lane >> 4, l16 = lane & 15;

    f32x4 acc[4][4];
    #pragma unroll
    for (int a = 0; a < 4; ++a)
        #pragma unroll
        for (int b = 0; b < 4; ++b)
            acc[a][b] = (f32x4){0.f, 0.f, 0.f, 0.f};

    const float* Bexp = B + (size_t)e * K * N + (size_t)nt * 128;

    for (int k0 = 0; k0 < K; k0 += 32) {
        // stage A tile: 128 rows x 32 cols bf16, 16B chunks
        #pragma unroll
        for (int c = 0; c < 2; ++c) {
            int idx = tid + c * 256;           // 0..511
            int row = idx >> 2, seg = idx & 3;
            int lr = mt * 128 + row;
            int lrc = (lr < cnt) ? lr : (cnt - 1);   // clamp: garbage rows masked at store
            const unsigned short* src = A + (size_t)(off + lrc) * K + k0 + seg * 8;
            *(s16x8*)(&As[row][seg * 8]) = *(const s16x8*)src;
        }
        // stage B tile with transpose + fp32->bf16: 32 k-rows x 128 n-cols
        #pragma unroll
        for (int c = 0; c < 4; ++c) {
            int idx = tid + c * 256;           // 0..1023
            int k = idx >> 5, nv = idx & 31;
            const float4 v = *(const float4*)(Bexp + (size_t)(k0 + k) * N + nv * 4);
            Bs[nv*4 + 0][k] = f2bf(v.x);
            Bs[nv*4 + 1][k] = f2bf(v.y);
            Bs[nv*4 + 2][k] = f2bf(v.z);
            Bs[nv*4 + 3][k] = f2bf(v.w);
        }
        __syncthreads();

        s16x8 af[4], bfr[4];
        #pragma unroll
        for (int mi = 0; mi < 4; ++mi)
            af[mi] = *(const s16x8*)(&As[wm*64 + mi*16 + l16][quad*8]);
        #pragma unroll
        for (int ni = 0; ni < 4; ++ni)
            bfr[ni] = *(const s16x8*)(&Bs[wn*64 + ni*16 + l16][quad*8]);
        #pragma unroll
        for (int mi = 0; mi < 4; ++mi)
            #pragma unroll
            for (int ni = 0; ni < 4; ++ni)
                acc[mi][ni] = __builtin_amdgcn_mfma_f32_16x16x32_bf16(af[mi], bfr[ni], acc[mi][ni], 0, 0, 0);
        __syncthreads();
    }

    // epilogue: C/D layout col=lane&15, row=quad*4+reg
    #pragma unroll
    for (int ni = 0; ni < 4; ++ni) {
        int col = nt*128 + wn*64 + ni*16 + l16;
        float bv = bias[(size_t)e * N + col];
        #pragma unroll
        for (int mi = 0; mi < 4; ++mi) {
            #pragma unroll
            for (int r = 0; r < 4; ++r) {
                int lm = mt*128 + wm*64 + mi*16 + quad*4 + r;
                if (lm < cnt) {
                    float x = acc[mi][ni][r] + bv;
                    if (doGelu) {
                        x = 0.5f * x * (1.0f + erff(x * 0.70710678118654752440f));
                        Gout[(size_t)(off + lm) * N + col] = f2bf(x);
                    } else {
                        int tok = perm[off + lm];
                        float* o = Yout + (size_t)tok * N + col;
                        if (doAdd) *o = *o + x; else *o = x;
                    }
                }
            }
        }
    }
}

extern "C" void kernel_launch(void* const* d_in, const int* in_sizes, int n_in,
                              void* d_out, int out_size, void* d_ws, size_t ws_size,
                              hipStream_t stream) {
    (void)in_sizes; (void)n_in; (void)out_size; (void)ws_size;
    const float* h   = (const float*)d_in[0];
    const float* Wsc = (const float*)d_in[1];
    const float* bsc = (const float*)d_in[2];
    const float* W1c = (const float*)d_in[3];
    const float* b1c = (const float*)d_in[4];
    const float* W2c = (const float*)d_in[5];
    const float* b2c = (const float*)d_in[6];
    const float* Wsu = (const float*)d_in[7];
    const float* bsu = (const float*)d_in[8];
    const float* W1u = (const float*)d_in[9];
    const float* b1u = (const float*)d_in[10];
    const float* W2u = (const float*)d_in[11];
    const float* b2u = (const float*)d_in[12];
    float* out = (float*)d_out;

    char* w = (char*)d_ws;
    size_t o = 0;
    auto carve = [&](size_t bytes) -> char* {
        char* p = w + o; o += (bytes + 255) & ~(size_t)255; return p;
    };
    int*   route_c = (int*)carve(NTOK * 4);
    float* pmax_c  = (float*)carve(NTOK * 4);
    int*   route_u = (int*)carve(NTOK * 4);
    float* pmax_u  = (float*)carve(NTOK * 4);
    int*   dropped = (int*)carve(NTOK * 4);
    int*   counts  = (int*)carve(8 * 4);
    int*   offc    = (int*)carve(5 * 4);
    int*   offu    = (int*)carve(5 * 4);
    int*   cur     = (int*)carve(8 * 4);
    int*   permc   = (int*)carve(NTOK * 4);
    int*   permu   = (int*)carve(NTOK * 4);
    unsigned short* Xc = (unsigned short*)carve((size_t)NTOK * HDIM * 2);
    unsigned short* Xu = (unsigned short*)carve((size_t)NTOK * HDIM * 2);
    unsigned short* G  = (unsigned short*)carve((size_t)NTOK * FDIM * 2);

    int capacity = NTOK / NEXP;   // int(1.0 * 4096 / 4) = 1024

    route_kernel<<<NTOK, 256, 0, stream>>>(h, Wsc, bsc, Wsu, bsu,
                                           route_c, pmax_c, route_u, pmax_u, counts);
    rank_kernel<<<NTOK, 256, 0, stream>>>(route_c, pmax_c, dropped, capacity);
    count_kernel<<<NTOK/256, 256, 0, stream>>>(route_c, route_u, dropped, counts);
    offsets_kernel<<<1, 64, 0, stream>>>(counts, offc, offu, cur);
    scatter_kernel<<<NTOK/256, 256, 0, stream>>>(route_c, route_u, dropped,
                                                 offc, offu, cur, permc, permu);
    gather_kernel<<<NTOK, 256, 0, stream>>>(h, permc, offc + 4, Xc);
    gather_kernel<<<NTOK, 256, 0, stream>>>(h, permu, offu + 4, Xu);

    // common path: FFN1 (gelu -> G), FFN2 (scatter to out)
    ffn_gemm<<<dim3(FDIM/128, 32, 4), 256, 0, stream>>>(
        Xc, W1c, b1c, offc, G, nullptr, nullptr, HDIM, FDIM, 1, 0);
    ffn_gemm<<<dim3(HDIM/128, 32, 4), 256, 0, stream>>>(
        G, W2c, b2c, offc, nullptr, out, permc, FDIM, HDIM, 0, 0);
    // unique path: only dropped tokens, accumulated into out
    ffn_gemm<<<dim3(FDIM/128, 32, 4), 256, 0, stream>>>(
        Xu, W1u, b1u, offu, G, nullptr, nullptr, HDIM, FDIM, 1, 0);
    ffn_gemm<<<dim3(HDIM/128, 32, 4), 256, 0, stream>>>(
        G, W2u, b2u, offu, nullptr, out, permu, FDIM, HDIM, 0, 1);
}

// Round 2
// 511.622 us; speedup vs baseline: 1.5701x; 1.5701x over previous
//
#include <hip/hip_runtime.h>
#include <hip/hip_bf16.h>
#include <math.h>

#define NTOK 4096
#define HDIM 768
#define FDIM 3072
#define NEXP 4
#define MAXT 36

typedef __attribute__((ext_vector_type(4))) float f32x4;
typedef __attribute__((ext_vector_type(8))) short s16x8;

__device__ __forceinline__ unsigned short f2bf(float f) {
    union { float f; unsigned int u; } v; v.f = f;
    unsigned int u = v.u;
    unsigned int r = (u + 0x7fffu + ((u >> 16) & 1u)) >> 16;
    return (unsigned short)r;
}

// async global->LDS, 16B per lane. ldsdst must be wave-uniform; HW adds lane*16.
__device__ __forceinline__ void gload_lds16(const unsigned short* g, unsigned short* l) {
    __builtin_amdgcn_global_load_lds((const __attribute__((address_space(1))) void*)g,
                                     (__attribute__((address_space(3))) void*)l, 16, 0, 0);
}

// ---------------- routing: one wave per token ------------------------------------
__global__ void __launch_bounds__(256) route_kernel(
    const float* __restrict__ h, const float* __restrict__ Wsc, const float* __restrict__ bsc,
    const float* __restrict__ Wsu, const float* __restrict__ bsu,
    int* __restrict__ route_c, float* __restrict__ pmax_c,
    int* __restrict__ route_u, float* __restrict__ pmax_u,
    int* __restrict__ counts)
{
    if (blockIdx.x == 0 && threadIdx.x < 8) counts[threadIdx.x] = 0;
    int tok = blockIdx.x * 4 + (threadIdx.x >> 6);
    int lane = threadIdx.x & 63;
    const float* hr = h + (size_t)tok * HDIM;
    float ac[4] = {0.f,0.f,0.f,0.f}, au[4] = {0.f,0.f,0.f,0.f};
    for (int k = lane; k < HDIM; k += 64) {
        float x = hr[k];
        const float4 wc = *(const float4*)(Wsc + k * 4);
        const float4 wu = *(const float4*)(Wsu + k * 4);
        ac[0] += x * wc.x; ac[1] += x * wc.y; ac[2] += x * wc.z; ac[3] += x * wc.w;
        au[0] += x * wu.x; au[1] += x * wu.y; au[2] += x * wu.z; au[3] += x * wu.w;
    }
    #pragma unroll
    for (int off = 32; off > 0; off >>= 1) {
        #pragma unroll
        for (int j = 0; j < 4; ++j) {
            ac[j] += __shfl_xor(ac[j], off);
            au[j] += __shfl_xor(au[j], off);
        }
    }
    if (lane == 0) {
        float lc[4], lu[4];
        #pragma unroll
        for (int j = 0; j < 4; ++j) { lc[j] = ac[j] + bsc[j]; lu[j] = au[j] + bsu[j]; }
        int bc = 0; float mc = lc[0];
        #pragma unroll
        for (int j = 1; j < 4; ++j) if (lc[j] > mc) { mc = lc[j]; bc = j; }
        float dc = 0.f;
        #pragma unroll
        for (int j = 0; j < 4; ++j) dc += expf(lc[j] - mc);
        route_c[tok] = bc; pmax_c[tok] = 1.0f / dc;
        int bu = 0; float mu = lu[0];
        #pragma unroll
        for (int j = 1; j < 4; ++j) if (lu[j] > mu) { mu = lu[j]; bu = j; }
        float du = 0.f;
        #pragma unroll
        for (int j = 0; j < 4; ++j) du += expf(lu[j] - mu);
        route_u[tok] = bu; pmax_u[tok] = 1.0f / du;
    }
}

// ---------------- capacity-drop: rank within expert group by (-pmax, index) ------
__global__ void __launch_bounds__(256) rank_kernel(
    const int* __restrict__ rc, const float* __restrict__ pc,
    int* __restrict__ dropped, int capacity)
{
    int i = blockIdx.x, t = threadIdx.x;
    int e = rc[i]; float pi = pc[i];
    int cnt = 0;
    for (int j = t; j < NTOK; j += 256) {
        if (rc[j] == e) {
            float pj = pc[j];
            if (pj > pi || (pj == pi && j < i)) cnt++;
        }
    }
    __shared__ int red[256];
    red[t] = cnt; __syncthreads();
    for (int s = 128; s > 0; s >>= 1) {
        if (t < s) red[t] += red[t+s];
        __syncthreads();
    }
    if (t == 0) dropped[i] = (red[0] >= capacity) ? 1 : 0;
}

__global__ void __launch_bounds__(256) count_kernel(
    const int* __restrict__ rc, const int* __restrict__ ru,
    const int* __restrict__ dropped, int* __restrict__ counts)
{
    int i = blockIdx.x * 256 + threadIdx.x;
    if (i >= NTOK) return;
    atomicAdd(&counts[rc[i]], 1);
    if (dropped[i]) atomicAdd(&counts[4 + ru[i]], 1);
}

__global__ void offsets_kernel(const int* __restrict__ counts,
                               int* __restrict__ offc, int* __restrict__ offu,
                               int* __restrict__ cur,
                               int* __restrict__ tabc, int* __restrict__ tabu)
{
    if (threadIdx.x == 0 && blockIdx.x == 0) {
        int oc = 0, ou = 0;
        for (int e = 0; e < 4; ++e) { offc[e] = oc; oc += counts[e]; }
        offc[4] = oc;
        for (int e = 0; e < 4; ++e) { offu[e] = ou; ou += counts[4+e]; }
        offu[4] = ou;
        for (int j = 0; j < 8; ++j) cur[j] = 0;
        int t = 0;
        for (int e = 0; e < 4; ++e) {
            int nt = (counts[e] + 127) >> 7;
            for (int m = 0; m < nt; ++m) { tabc[t*2] = e; tabc[t*2+1] = m; ++t; }
        }
        for (; t < MAXT; ++t) { tabc[t*2] = -1; tabc[t*2+1] = 0; }
        t = 0;
        for (int e = 0; e < 4; ++e) {
            int nt = (counts[4+e] + 127) >> 7;
            for (int m = 0; m < nt; ++m) { tabu[t*2] = e; tabu[t*2+1] = m; ++t; }
        }
        for (; t < MAXT; ++t) { tabu[t*2] = -1; tabu[t*2+1] = 0; }
    }
}

__global__ void __launch_bounds__(256) scatter_kernel(
    const int* __restrict__ rc, const int* __restrict__ ru, const int* __restrict__ dropped,
    const int* __restrict__ offc, const int* __restrict__ offu,
    int* __restrict__ cur, int* __restrict__ permc, int* __restrict__ permu)
{
    int i = blockIdx.x * 256 + threadIdx.x;
    if (i >= NTOK) return;
    int e = rc[i];
    int p = offc[e] + atomicAdd(&cur[e], 1);
    permc[p] = i;
    if (dropped[i]) {
        int eu = ru[i];
        int q = offu[eu] + atomicAdd(&cur[4 + eu], 1);
        permu[q] = i;
    }
}

// ---------------- gather tokens (sorted order) into bf16 -------------------------
__global__ void __launch_bounds__(192) gather_kernel(
    const float* __restrict__ h, const int* __restrict__ perm,
    const int* __restrict__ nvalid, unsigned short* __restrict__ Xs)
{
    int pos = blockIdx.x;
    if (pos >= *nvalid) return;
    int t = threadIdx.x;
    int tok = perm[pos];
    const float4 v = *(const float4*)(h + (size_t)tok * HDIM + t * 4);
    ushort4 o;
    o.x = f2bf(v.x); o.y = f2bf(v.y); o.z = f2bf(v.z); o.w = f2bf(v.w);
    *(ushort4*)(Xs + (size_t)pos * HDIM + t * 4) = o;
}

// ---------------- weight transpose+convert: fp32 [E][K][N] -> bf16 [E][N][K] -----
__global__ void __launch_bounds__(256) wtrans_kernel(
    const float* __restrict__ W, unsigned short* __restrict__ Bt, int K, int N)
{
    int e = blockIdx.z;
    const float* We = W + (size_t)e * K * N;
    unsigned short* Be = Bt + (size_t)e * N * K;
    int k0 = blockIdx.y * 32, n0 = blockIdx.x * 32;
    __shared__ float t[32][33];
    int tid = threadIdx.x;
    int r = tid >> 3, c4 = (tid & 7) * 4;
    const float4 v = *(const float4*)(We + (size_t)(k0 + r) * N + n0 + c4);
    t[r][c4+0] = v.x; t[r][c4+1] = v.y; t[r][c4+2] = v.z; t[r][c4+3] = v.w;
    __syncthreads();
    int n = tid >> 3, kk = (tid & 7) * 4;
    ushort4 o;
    o.x = f2bf(t[kk+0][n]); o.y = f2bf(t[kk+1][n]);
    o.z = f2bf(t[kk+2][n]); o.w = f2bf(t[kk+3][n]);
    *(ushort4*)(Be + (size_t)(n0 + n) * K + k0 + kk) = o;
}

// ---------------- grouped GEMM: 128x128 tile, global_load_lds, swizzled LDS ------
// A bf16 [rows][K], Bt bf16 [E][N][K]. Split-K via gridDim.z (atomicAdd epilogue).
// doGelu: exact-GELU -> bf16 Gout[pos][N]. else: atomicAdd fp32 into Yout[perm[pos]][N].
__global__ void __launch_bounds__(256) ffn_gemm(
    const unsigned short* __restrict__ A, const unsigned short* __restrict__ Bt,
    const float* __restrict__ bias, const int* __restrict__ offs,
    const int* __restrict__ tab,
    unsigned short* __restrict__ Gout, float* __restrict__ Yout,
    const int* __restrict__ perm, int K, int N, int doGelu)
{
    int e = tab[blockIdx.y * 2];
    if (e < 0) return;
    int mt = tab[blockIdx.y * 2 + 1];
    int off = offs[e];
    int cnt = offs[e + 1] - off;
    int nt = blockIdx.x;
    int klen = K / gridDim.z;
    int kbeg = blockIdx.z * klen, kend = kbeg + klen;

    __shared__ unsigned short As[4096];   // 128 rows x 32 cols bf16, chunk-swizzled
    __shared__ unsigned short Bs[4096];

    int tid = threadIdx.x;
    int lane = tid & 63, wave = tid >> 6;
    int wm = wave >> 1, wn = wave & 1;
    int quad = lane >> 4, l16 = lane & 15;

    f32x4 acc[4][4];
    #pragma unroll
    for (int a = 0; a < 4; ++a)
        #pragma unroll
        for (int b = 0; b < 4; ++b)
            acc[a][b] = (f32x4){0.f, 0.f, 0.f, 0.f};

    // staging: 512 16B-chunks per tile; thread handles chunks tid and tid+256.
    // LDS slot (row, s) holds global segment s ^ swz(row), swz = (row&3)^((row>>2)&3)
    int r0 = tid >> 2, s0 = tid & 3;
    int r1 = (tid + 256) >> 2;            // s1 == s0
    int seg0 = (s0 ^ ((r0 & 3) ^ ((r0 >> 2) & 3))) * 8;
    int seg1 = (s0 ^ ((r1 & 3) ^ ((r1 >> 2) & 3))) * 8;
    int ar0 = mt * 128 + r0; if (ar0 >= cnt) ar0 = cnt - 1;
    int ar1 = mt * 128 + r1; if (ar1 >= cnt) ar1 = cnt - 1;

    const unsigned short* Ae = A + (size_t)off * K;
    const unsigned short* Be = Bt + ((size_t)e * N + (size_t)nt * 128) * K;
    const unsigned short* asrc0 = Ae + (size_t)ar0 * K + seg0;
    const unsigned short* asrc1 = Ae + (size_t)ar1 * K + seg1;
    const unsigned short* bsrc0 = Be + (size_t)r0 * K + seg0;
    const unsigned short* bsrc1 = Be + (size_t)r1 * K + seg1;
    unsigned short* al0 = &As[wave * 512];          // HW adds lane*16B
    unsigned short* al1 = &As[2048 + wave * 512];
    unsigned short* bl0 = &Bs[wave * 512];
    unsigned short* bl1 = &Bs[2048 + wave * 512];

    // fragment read column-chunk (swizzled); uniform in mi since base%16==0
    int cca = quad ^ ((l16 & 3) ^ ((l16 >> 2) & 3));

    for (int k0 = kbeg; k0 < kend; k0 += 32) {
        gload_lds16(asrc0 + k0, al0);
        gload_lds16(asrc1 + k0, al1);
        gload_lds16(bsrc0 + k0, bl0);
        gload_lds16(bsrc1 + k0, bl1);
        __syncthreads();

        s16x8 af[4], bf[4];
        #pragma unroll
        for (int mi = 0; mi < 4; ++mi)
            af[mi] = *(const s16x8*)&As[(wm * 64 + mi * 16 + l16) * 32 + cca * 8];
        #pragma unroll
        for (int ni = 0; ni < 4; ++ni)
            bf[ni] = *(const s16x8*)&Bs[(wn * 64 + ni * 16 + l16) * 32 + cca * 8];
        #pragma unroll
        for (int mi = 0; mi < 4; ++mi)
            #pragma unroll
            for (int ni = 0; ni < 4; ++ni)
                acc[mi][ni] = __builtin_amdgcn_mfma_f32_16x16x32_bf16(af[mi], bf[ni], acc[mi][ni], 0, 0, 0);
        __syncthreads();
    }

    // epilogue: C/D layout col=lane&15, row=quad*4+reg
    #pragma unroll
    for (int ni = 0; ni < 4; ++ni) {
        int col = nt * 128 + wn * 64 + ni * 16 + l16;
        float bv = (blockIdx.z == 0) ? bias[(size_t)e * N + col] : 0.f;
        #pragma unroll
        for (int mi = 0; mi < 4; ++mi) {
            #pragma unroll
            for (int r = 0; r < 4; ++r) {
                int lm = mt * 128 + wm * 64 + mi * 16 + quad * 4 + r;
                if (lm < cnt) {
                    float x = acc[mi][ni][r] + bv;
                    if (doGelu) {
                        x = 0.5f * x * (1.0f + erff(x * 0.70710678118654752440f));
                        Gout[(size_t)(off + lm) * N + col] = f2bf(x);
                    } else {
                        atomicAdd(&Yout[(size_t)perm[off + lm] * N + col], x);
                    }
                }
            }
        }
    }
}

extern "C" void kernel_launch(void* const* d_in, const int* in_sizes, int n_in,
                              void* d_out, int out_size, void* d_ws, size_t ws_size,
                              hipStream_t stream) {
    (void)in_sizes; (void)n_in; (void)out_size; (void)ws_size;
    const float* h   = (const float*)d_in[0];
    const float* Wsc = (const float*)d_in[1];
    const float* bsc = (const float*)d_in[2];
    const float* W1c = (const float*)d_in[3];
    const float* b1c = (const float*)d_in[4];
    const float* W2c = (const float*)d_in[5];
    const float* b2c = (const float*)d_in[6];
    const float* Wsu = (const float*)d_in[7];
    const float* bsu = (const float*)d_in[8];
    const float* W1u = (const float*)d_in[9];
    const float* b1u = (const float*)d_in[10];
    const float* W2u = (const float*)d_in[11];
    const float* b2u = (const float*)d_in[12];
    float* out = (float*)d_out;

    char* w = (char*)d_ws;
    size_t o = 0;
    auto carve = [&](size_t bytes) -> char* {
        char* p = w + o; o += (bytes + 255) & ~(size_t)255; return p;
    };
    int*   route_c = (int*)carve(NTOK * 4);
    float* pmax_c  = (float*)carve(NTOK * 4);
    int*   route_u = (int*)carve(NTOK * 4);
    float* pmax_u  = (float*)carve(NTOK * 4);
    int*   dropped = (int*)carve(NTOK * 4);
    int*   counts  = (int*)carve(8 * 4);
    int*   offc    = (int*)carve(5 * 4);
    int*   offu    = (int*)carve(5 * 4);
    int*   cur     = (int*)carve(8 * 4);
    int*   permc   = (int*)carve(NTOK * 4);
    int*   permu   = (int*)carve(NTOK * 4);
    int*   tabc    = (int*)carve(MAXT * 2 * 4);
    int*   tabu    = (int*)carve(MAXT * 2 * 4);
    unsigned short* Xc  = (unsigned short*)carve((size_t)NTOK * HDIM * 2);
    unsigned short* Xu  = (unsigned short*)carve((size_t)NTOK * HDIM * 2);
    unsigned short* G   = (unsigned short*)carve((size_t)NTOK * FDIM * 2);
    unsigned short* BtA = (unsigned short*)carve((size_t)NEXP * HDIM * FDIM * 2);
    unsigned short* BtB = (unsigned short*)carve((size_t)NEXP * HDIM * FDIM * 2);

    int capacity = NTOK / NEXP;   // int(1.0 * 4096 / 4) = 1024

    hipMemsetAsync(out, 0, (size_t)NTOK * HDIM * 4, stream);

    route_kernel<<<NTOK/4, 256, 0, stream>>>(h, Wsc, bsc, Wsu, bsu,
                                             route_c, pmax_c, route_u, pmax_u, counts);
    rank_kernel<<<NTOK, 256, 0, stream>>>(route_c, pmax_c, dropped, capacity);
    count_kernel<<<NTOK/256, 256, 0, stream>>>(route_c, route_u, dropped, counts);
    offsets_kernel<<<1, 64, 0, stream>>>(counts, offc, offu, cur, tabc, tabu);
    scatter_kernel<<<NTOK/256, 256, 0, stream>>>(route_c, route_u, dropped,
                                                 offc, offu, cur, permc, permu);
    gather_kernel<<<NTOK, 192, 0, stream>>>(h, permc, offc + 4, Xc);
    gather_kernel<<<NTOK, 192, 0, stream>>>(h, permu, offu + 4, Xu);

    // ---- common path ----
    wtrans_kernel<<<dim3(FDIM/32, HDIM/32, NEXP), 256, 0, stream>>>(W1c, BtA, HDIM, FDIM);
    wtrans_kernel<<<dim3(HDIM/32, FDIM/32, NEXP), 256, 0, stream>>>(W2c, BtB, FDIM, HDIM);
    ffn_gemm<<<dim3(FDIM/128, MAXT, 1), 256, 0, stream>>>(
        Xc, BtA, b1c, offc, tabc, G, nullptr, nullptr, HDIM, FDIM, 1);
    ffn_gemm<<<dim3(HDIM/128, MAXT, 2), 256, 0, stream>>>(
        G, BtB, b2c, offc, tabc, nullptr, out, permc, FDIM, HDIM, 0);

    // ---- unique path (dropped tokens only), accumulated into out ----
    wtrans_kernel<<<dim3(FDIM/32, HDIM/32, NEXP), 256, 0, stream>>>(W1u, BtA, HDIM, FDIM);
    wtrans_kernel<<<dim3(HDIM/32, FDIM/32, NEXP), 256, 0, stream>>>(W2u, BtB, FDIM, HDIM);
    ffn_gemm<<<dim3(FDIM/128, MAXT, 1), 256, 0, stream>>>(
        Xu, BtA, b1u, offu, tabu, G, nullptr, nullptr, HDIM, FDIM, 1);
    ffn_gemm<<<dim3(HDIM/128, MAXT, 2), 256, 0, stream>>>(
        G, BtB, b2u, offu, tabu, nullptr, out, permu, FDIM, HDIM, 0);
}